// Round 1
// baseline (373.073 us; speedup 1.0000x reference)
//
#include <hip/hip_runtime.h>

// SpMM scatter: out[row[e]] += values[e] * x[col[e]]
// row sorted  ->  node-parallel segmented reduction, no atomics, no memset.
// One 64-lane wave per node; lane = feature index (D=64 exactly one wave).

constexpr int D = 64;

__global__ __launch_bounds__(256) void spmm_node_kernel(
    const int* __restrict__ row,
    const int* __restrict__ col,
    const float* __restrict__ val,
    const float* __restrict__ x,
    float* __restrict__ out,
    int nEdges, int nNodes)
{
    const int wid  = (blockIdx.x * blockDim.x + threadIdx.x) >> 6;  // node id
    const int lane = threadIdx.x & 63;                               // feature id
    if (wid >= nNodes) return;

    // lower_bound(row, wid): first e with row[e] >= wid
    int lo = 0, hi = nEdges;
    while (lo < hi) {
        int mid = (lo + hi) >> 1;
        if (row[mid] < wid) lo = mid + 1; else hi = mid;
    }
    const int start = lo;

    // lower_bound(row, wid+1): first e with row[e] >= wid+1
    hi = nEdges;
    while (lo < hi) {
        int mid = (lo + hi) >> 1;
        if (row[mid] < wid + 1) lo = mid + 1; else hi = mid;
    }
    const int end = lo;

    float acc = 0.0f;
    for (int e = start; e < end; ++e) {
        const int   c = col[e];            // wave-uniform scalar load
        const float v = val[e];            // wave-uniform scalar load
        acc = fmaf(v, x[(size_t)c * D + lane], acc);  // 256B coalesced gather
    }
    out[(size_t)wid * D + lane] = acc;     // fully coalesced store, covers all nodes
}

extern "C" void kernel_launch(void* const* d_in, const int* in_sizes, int n_in,
                              void* d_out, int out_size, void* d_ws, size_t ws_size,
                              hipStream_t stream)
{
    const int*   row = (const int*)  d_in[0];
    const int*   col = (const int*)  d_in[1];
    const float* val = (const float*)d_in[2];
    const float* x   = (const float*)d_in[3];
    float*       out = (float*)d_out;

    const int nEdges = in_sizes[0];
    const int nNodes = out_size / D;   // 100000

    const int threads_total = nNodes * 64;   // one wave per node
    const dim3 block(256);
    const dim3 grid((threads_total + block.x - 1) / block.x);
    spmm_node_kernel<<<grid, block, 0, stream>>>(row, col, val, x, out, nEdges, nNodes);
}

// Round 2
// 140.271 us; speedup vs baseline: 2.6597x; 2.6597x over previous
//
#include <hip/hip_runtime.h>

// SpMM scatter: out[row[e]] += values[e] * x[col[e]],  row sorted.
// Kernel 1: edge-parallel row_ptr build into d_ws (no atomics).
// Kernel 2: one 64-lane wave per node, 4 groups x 16 lanes, float4 gathers,
//           2x unroll -> 8 edges in flight per wave; shfl_xor cross-group
//           reduction; lanes 0-15 store the 256B output row.

constexpr int D  = 64;
constexpr int DV = D / 4;   // 16 float4 per feature row

__global__ __launch_bounds__(256) void build_row_ptr(
    const int* __restrict__ row, int* __restrict__ row_ptr,
    int nEdges, int nNodes)
{
    const int e = blockIdx.x * blockDim.x + threadIdx.x;
    if (e >= nEdges) return;
    const int r    = row[e];
    const int prev = (e == 0) ? -1 : row[e - 1];
    for (int n = prev + 1; n <= r; ++n) row_ptr[n] = e;     // lower_bound(row, n) = e
    if (e == nEdges - 1) {
        for (int n = r + 1; n <= nNodes; ++n) row_ptr[n] = nEdges;
    }
}

__device__ __forceinline__ void edge_body(
    const int* __restrict__ col, const float* __restrict__ val,
    const float4* __restrict__ x4, int sub, int e, int end, float4& acc)
{
    // two edges (e, e+4) prefetched together -> 2 gathers in flight per group
    const int  e1 = e + 4;
    const bool p1 = e1 < end;
    const int   c0 = col[e];
    const float v0 = val[e];
    int c1 = 0; float v1 = 0.f;
    if (p1) { c1 = col[e1]; v1 = val[e1]; }
    const float4 x0 = x4[(size_t)c0 * DV + sub];
    float4 x1 = {0.f, 0.f, 0.f, 0.f};
    if (p1) x1 = x4[(size_t)c1 * DV + sub];
    acc.x = fmaf(v0, x0.x, acc.x);
    acc.y = fmaf(v0, x0.y, acc.y);
    acc.z = fmaf(v0, x0.z, acc.z);
    acc.w = fmaf(v0, x0.w, acc.w);
    acc.x = fmaf(v1, x1.x, acc.x);
    acc.y = fmaf(v1, x1.y, acc.y);
    acc.z = fmaf(v1, x1.z, acc.z);
    acc.w = fmaf(v1, x1.w, acc.w);
}

__global__ __launch_bounds__(256) void spmm_wave4(
    const int* __restrict__ row_ptr,
    const int* __restrict__ col,
    const float* __restrict__ val,
    const float4* __restrict__ x4,
    float4* __restrict__ out4,
    int nNodes)
{
    const int wid = (blockIdx.x * blockDim.x + threadIdx.x) >> 6;   // node id
    if (wid >= nNodes) return;
    const int lane  = threadIdx.x & 63;
    const int group = lane >> 4;    // 0..3 -> edge stripe
    const int sub   = lane & 15;    // 0..15 -> float4 index within row

    const int start = row_ptr[wid];
    const int end   = row_ptr[wid + 1];

    float4 acc = {0.f, 0.f, 0.f, 0.f};
    for (int e = start + group; e < end; e += 8)
        edge_body(col, val, x4, sub, e, end, acc);

    // reduce partial sums across the 4 groups (lanes ^16, ^32)
    #pragma unroll
    for (int off = 16; off <= 32; off <<= 1) {
        acc.x += __shfl_xor(acc.x, off, 64);
        acc.y += __shfl_xor(acc.y, off, 64);
        acc.z += __shfl_xor(acc.z, off, 64);
        acc.w += __shfl_xor(acc.w, off, 64);
    }
    if (group == 0) out4[(size_t)wid * DV + sub] = acc;   // 256B coalesced store
}

// Fallback if d_ws is too small for row_ptr: inline binary search (R1 behavior
// for the segment bounds, but with the 8-way-MLP edge loop).
__global__ __launch_bounds__(256) void spmm_wave4_bs(
    const int* __restrict__ row,
    const int* __restrict__ col,
    const float* __restrict__ val,
    const float4* __restrict__ x4,
    float4* __restrict__ out4,
    int nEdges, int nNodes)
{
    const int wid = (blockIdx.x * blockDim.x + threadIdx.x) >> 6;
    if (wid >= nNodes) return;
    const int lane  = threadIdx.x & 63;
    const int group = lane >> 4;
    const int sub   = lane & 15;

    int lo = 0, hi = nEdges;
    while (lo < hi) { int mid = (lo + hi) >> 1; if (row[mid] < wid) lo = mid + 1; else hi = mid; }
    const int start = lo;
    hi = nEdges;
    while (lo < hi) { int mid = (lo + hi) >> 1; if (row[mid] < wid + 1) lo = mid + 1; else hi = mid; }
    const int end = lo;

    float4 acc = {0.f, 0.f, 0.f, 0.f};
    for (int e = start + group; e < end; e += 8)
        edge_body(col, val, x4, sub, e, end, acc);

    #pragma unroll
    for (int off = 16; off <= 32; off <<= 1) {
        acc.x += __shfl_xor(acc.x, off, 64);
        acc.y += __shfl_xor(acc.y, off, 64);
        acc.z += __shfl_xor(acc.z, off, 64);
        acc.w += __shfl_xor(acc.w, off, 64);
    }
    if (group == 0) out4[(size_t)wid * DV + sub] = acc;
}

extern "C" void kernel_launch(void* const* d_in, const int* in_sizes, int n_in,
                              void* d_out, int out_size, void* d_ws, size_t ws_size,
                              hipStream_t stream)
{
    const int*    row = (const int*)   d_in[0];
    const int*    col = (const int*)   d_in[1];
    const float*  val = (const float*) d_in[2];
    const float4* x4  = (const float4*)d_in[3];
    float4*       out4 = (float4*)d_out;

    const int nEdges = in_sizes[0];
    const int nNodes = out_size / D;            // 100000

    const dim3 block(256);
    const dim3 gridMain(((size_t)nNodes * 64 + 255) / 256);

    const size_t rp_bytes = (size_t)(nNodes + 1) * sizeof(int);
    if (ws_size >= rp_bytes) {
        int* row_ptr = (int*)d_ws;
        build_row_ptr<<<dim3((nEdges + 255) / 256), block, 0, stream>>>(
            (const int*)d_in[0], row_ptr, nEdges, nNodes);
        spmm_wave4<<<gridMain, block, 0, stream>>>(row_ptr, (const int*)d_in[1],
                                                   val, x4, out4, nNodes);
    } else {
        spmm_wave4_bs<<<gridMain, block, 0, stream>>>(row, (const int*)d_in[1],
                                                      val, x4, out4, nEdges, nNodes);
    }
}